// Round 1
// baseline (835.959 us; speedup 1.0000x reference)
//
#include <hip/hip_runtime.h>

// LSTM: B=2048, T=512, I=1, H=64, O=1. PyTorch gate order i,f,g,o.
// Inputs (fp32): x[B,T,1], w_ih[256,1], w_hh[256,64], b_ih[256], b_hh[256],
//                w_lin[1,64], b_lin[1].  Output: out[B,1] fp32.
//
// Design: 1 WG (256 thr, 4 waves) per 4 batches. Grid=512 -> 2048 waves
// (2/SIMD, 2 WGs/CU). Matvec role: wave=gate block, lane=gate row, w_hh row
// in 64 VGPRs; h broadcast from LDS. Update role: wave=batch, lane=state j.
// Two barriers per step (both handoffs cross waves).

namespace {
constexpr int Bsz = 2048;
constexpr int Tsz = 512;
constexpr int Hsz = 64;
constexpr int NB  = 4;   // batches per workgroup
}

__device__ __forceinline__ float sigm(float x) {
    return 1.0f / (1.0f + __expf(-x));
}
__device__ __forceinline__ float tanh_fast(float x) {
    // overflow-safe: e = exp(-2|x|) in (0,1]
    float a = fabsf(x);
    float e = __expf(-2.0f * a);
    float t = (1.0f - e) / (1.0f + e);
    return copysignf(t, x);
}

__global__ __launch_bounds__(256, 2)
void lstm_fused(const float* __restrict__ x,      // [B,T]
                const float* __restrict__ w_ih,   // [256]
                const float* __restrict__ w_hh,   // [256,64]
                const float* __restrict__ b_ih,   // [256]
                const float* __restrict__ b_hh,   // [256]
                const float* __restrict__ w_lin,  // [64]
                const float* __restrict__ b_lin,  // [1]
                float* __restrict__ out)          // [B]
{
    __shared__ __align__(16) float x_lds[NB][Tsz];     // 8 KB
    __shared__ __align__(16) float h_lds[NB][Hsz];     // 1 KB
    __shared__ __align__(16) float g_buf[4][NB][Hsz];  // 4 KB

    const int tid  = threadIdx.x;
    const int wave = tid >> 6;
    const int lane = tid & 63;
    const int b0   = blockIdx.x * NB;

    // ---- stage x[b0..b0+3][:] into LDS (coalesced float4) ----
    {
        const int nf4 = NB * Tsz / 4;          // 512 float4
        for (int i = tid; i < nf4; i += 256) {
            const int b  = i >> 7;             // Tsz/4 = 128 f4 per row
            const int c4 = i & 127;
            reinterpret_cast<float4*>(x_lds[b])[c4] =
                reinterpret_cast<const float4*>(x + (size_t)(b0 + b) * Tsz)[c4];
        }
    }
    // init h = 0 (4*64 = 256 threads, one each)
    h_lds[wave][lane] = 0.0f;

    // ---- matvec role constants: gate = wave*64 + lane ----
    const int gate = wave * Hsz + lane;
    float4 wv[16];
    #pragma unroll
    for (int i = 0; i < 16; ++i)
        wv[i] = reinterpret_cast<const float4*>(w_hh + (size_t)gate * Hsz)[i];
    const float wih  = w_ih[gate];
    const float bias = b_ih[gate] + b_hh[gate];

    // ---- update role state: (batch = wave, j = lane) ----
    float c = 0.0f;
    float h = 0.0f;

    __syncthreads();

    for (int t = 0; t < Tsz; ++t) {
        // ----- matvec: acc[b] = x[b][t]*wih + bias + h[b] . w_row -----
        float acc[NB];
        #pragma unroll
        for (int b = 0; b < NB; ++b)
            acc[b] = fmaf(x_lds[b][t], wih, bias);

        #pragma unroll
        for (int c4 = 0; c4 < 16; ++c4) {
            const float4 w4  = wv[c4];
            const float4 hv0 = reinterpret_cast<const float4*>(h_lds[0])[c4];
            const float4 hv1 = reinterpret_cast<const float4*>(h_lds[1])[c4];
            const float4 hv2 = reinterpret_cast<const float4*>(h_lds[2])[c4];
            const float4 hv3 = reinterpret_cast<const float4*>(h_lds[3])[c4];
            acc[0] = fmaf(hv0.x, w4.x, acc[0]);
            acc[0] = fmaf(hv0.y, w4.y, acc[0]);
            acc[0] = fmaf(hv0.z, w4.z, acc[0]);
            acc[0] = fmaf(hv0.w, w4.w, acc[0]);
            acc[1] = fmaf(hv1.x, w4.x, acc[1]);
            acc[1] = fmaf(hv1.y, w4.y, acc[1]);
            acc[1] = fmaf(hv1.z, w4.z, acc[1]);
            acc[1] = fmaf(hv1.w, w4.w, acc[1]);
            acc[2] = fmaf(hv2.x, w4.x, acc[2]);
            acc[2] = fmaf(hv2.y, w4.y, acc[2]);
            acc[2] = fmaf(hv2.z, w4.z, acc[2]);
            acc[2] = fmaf(hv2.w, w4.w, acc[2]);
            acc[3] = fmaf(hv3.x, w4.x, acc[3]);
            acc[3] = fmaf(hv3.y, w4.y, acc[3]);
            acc[3] = fmaf(hv3.z, w4.z, acc[3]);
            acc[3] = fmaf(hv3.w, w4.w, acc[3]);
        }

        #pragma unroll
        for (int b = 0; b < NB; ++b)
            g_buf[wave][b][lane] = acc[b];   // wave = gate block here

        __syncthreads();

        // ----- state update: thread owns (batch=wave, j=lane) -----
        {
            const float gi = g_buf[0][wave][lane];
            const float gf = g_buf[1][wave][lane];
            const float gg = g_buf[2][wave][lane];
            const float go = g_buf[3][wave][lane];

            const float ig = sigm(gi);
            const float fg = sigm(gf);
            const float tg = tanh_fast(gg);
            const float og = sigm(go);

            c = fmaf(fg, c, ig * tg);
            h = og * tanh_fast(c);
            h_lds[wave][lane] = h;
        }

        __syncthreads();
    }

    // ---- out[b0+wave] = sum_j h[j]*w_lin[j] + b_lin ----
    float p = h * w_lin[lane];
    #pragma unroll
    for (int off = 32; off > 0; off >>= 1)
        p += __shfl_xor(p, off, 64);
    if (lane == 0)
        out[b0 + wave] = p + b_lin[0];
}

extern "C" void kernel_launch(void* const* d_in, const int* in_sizes, int n_in,
                              void* d_out, int out_size, void* d_ws, size_t ws_size,
                              hipStream_t stream) {
    const float* x     = (const float*)d_in[0];
    const float* w_ih  = (const float*)d_in[1];
    const float* w_hh  = (const float*)d_in[2];
    const float* b_ih  = (const float*)d_in[3];
    const float* b_hh  = (const float*)d_in[4];
    const float* w_lin = (const float*)d_in[5];
    const float* b_lin = (const float*)d_in[6];
    float* out = (float*)d_out;

    dim3 grid(Bsz / NB);   // 512
    dim3 block(256);
    lstm_fused<<<grid, block, 0, stream>>>(x, w_ih, w_hh, b_ih, b_hh,
                                           w_lin, b_lin, out);
}

// Round 2
// 433.319 us; speedup vs baseline: 1.9292x; 1.9292x over previous
//
#include <hip/hip_runtime.h>

// LSTM B=2048, T=512, I=1, H=64, O=1 (PyTorch gate order i,f,g,o).
// MFMA-based step GEMM: G[4x256] = H[4x64] @ W^T via split-bf16
// (H_hi*W_hi + H_hi*W_lo + H_lo*W_hi), fp32 accumulate -> ~fp32 accuracy.
// WG = 256 thr (4 waves) per 4 batches; grid = 512 (2 WG/CU).
// Wave w owns gates [64w,64w+64) = 4 MFMA N-tiles; W frags in VGPRs.
// h staged in LDS in A-fragment layout, XOR-swizzled (byte ^= (row&7)<<4).

typedef float  f32x4  __attribute__((ext_vector_type(4)));
typedef __bf16 bf16x8 __attribute__((ext_vector_type(8)));

namespace {
constexpr int Bsz = 2048;
constexpr int Tsz = 512;
constexpr int Hsz = 64;
constexpr int NB  = 4;    // batches per workgroup
}

__device__ __forceinline__ float sigm(float x) {
    return 1.0f / (1.0f + __expf(-x));
}
__device__ __forceinline__ float tanh_fast(float x) {
    float a = fabsf(x);
    float e = __expf(-2.0f * a);          // in (0,1]
    float t = (1.0f - e) / (1.0f + e);
    return copysignf(t, x);
}

// byte offset into hA plane: [split][row(16)][128 bytes of k], swizzled
__device__ __forceinline__ int ha_off(int split, int r, int kbyte) {
    return split * 2048 + r * 128 + (kbyte ^ ((r & 7) << 4));
}

__global__ __launch_bounds__(256, 2)
void lstm_mfma(const float* __restrict__ x,      // [B,T]
               const float* __restrict__ w_ih,   // [256]
               const float* __restrict__ w_hh,   // [256,64]
               const float* __restrict__ b_ih,   // [256]
               const float* __restrict__ b_hh,   // [256]
               const float* __restrict__ w_lin,  // [64]
               const float* __restrict__ b_lin,  // [1]
               float* __restrict__ out)          // [B]
{
    __shared__ float x_lds[Tsz][NB];                    // 8 KB, [t][b]
    __shared__ __align__(16) char  hA[2 * 16 * 128];    // 4 KB, A-frag layout
    __shared__ __align__(16) float g_raw[256 * NB];     // 4 KB, [gate][b]

    const int tid = threadIdx.x;
    const int wv  = tid >> 6;
    const int ln  = tid & 63;
    const int b0  = blockIdx.x * NB;

    // ---- stage x transposed into LDS: x_lds[t][b] ----
    #pragma unroll
    for (int it = 0; it < 2; ++it) {
        int i  = tid + it * 256;          // 0..511
        int b  = i >> 7;                  // 128 float4 per batch row
        int t4 = i & 127;
        float4 v = reinterpret_cast<const float4*>(x + (size_t)(b0 + b) * Tsz)[t4];
        x_lds[t4 * 4 + 0][b] = v.x;
        x_lds[t4 * 4 + 1][b] = v.y;
        x_lds[t4 * 4 + 2][b] = v.z;
        x_lds[t4 * 4 + 3][b] = v.w;
    }

    // ---- W fragments (one-time): wave wv owns gates [wv*64, wv*64+64) ----
    // B-operand for tile tn, k-chunk kc: lane supplies W[gate = base+ (ln&15)]
    // [k = kc*32 + (ln>>4)*8 + e], e=0..7 (same k-slot mapping as A).
    bf16x8 Whi[4][2], Wlo[4][2];
    {
        const int col = ln & 15, grp = ln >> 4;
        #pragma unroll
        for (int tn = 0; tn < 4; ++tn) {
            const int gate = wv * 64 + tn * 16 + col;
            const float* wrow = w_hh + (size_t)gate * Hsz;
            #pragma unroll
            for (int kc = 0; kc < 2; ++kc) {
                const int kb = kc * 32 + grp * 8;
                bf16x8 hi, lo;
                #pragma unroll
                for (int e = 0; e < 8; ++e) {
                    float w  = wrow[kb + e];
                    __bf16 wh = (__bf16)w;
                    float  wr = w - (float)wh;
                    hi[e] = wh;
                    lo[e] = (__bf16)wr;
                }
                Whi[tn][kc] = hi;
                Wlo[tn][kc] = lo;
            }
        }
    }

    // ---- phase-2 ownership: thread = (b = tid&3, j = tid>>2) ----
    const int pb = tid & 3;
    const int pj = tid >> 2;
    float wih[4], bias[4];
    #pragma unroll
    for (int g4 = 0; g4 < 4; ++g4) {
        wih[g4]  = w_ih[g4 * 64 + pj];
        bias[g4] = b_ih[g4 * 64 + pj] + b_hh[g4 * 64 + pj];
    }
    const float wlin = w_lin[pj];

    // zero h state in hA (rows 0..3 only are real)
    *(__bf16*)(hA + ha_off(0, pb, pj * 2)) = (__bf16)0.0f;
    *(__bf16*)(hA + ha_off(1, pb, pj * 2)) = (__bf16)0.0f;

    float c = 0.0f, h = 0.0f;

    // A-fragment byte offsets for this lane (row = ln&15, k-group = ln>>4)
    const int arow  = ln & 15;
    const int agrp  = ln >> 4;
    const int aoff0 = ha_off(0, arow, 0 * 64 + agrp * 16);  // hi, kc=0
    const int aoff1 = ha_off(0, arow, 1 * 64 + agrp * 16);  // hi, kc=1
    const int boff0 = ha_off(1, arow, 0 * 64 + agrp * 16);  // lo, kc=0
    const int boff1 = ha_off(1, arow, 1 * 64 + agrp * 16);  // lo, kc=1

    __syncthreads();

    for (int t = 0; t < Tsz; ++t) {
        // ===== phase 1: MFMA G = H @ W^T (all 4 waves) =====
        bf16x8 Ahi0 = *(const bf16x8*)(hA + aoff0);
        bf16x8 Ahi1 = *(const bf16x8*)(hA + aoff1);
        bf16x8 Alo0 = *(const bf16x8*)(hA + boff0);
        bf16x8 Alo1 = *(const bf16x8*)(hA + boff1);

        f32x4 acc[4];
        #pragma unroll
        for (int tn = 0; tn < 4; ++tn) acc[tn] = (f32x4){0.f, 0.f, 0.f, 0.f};

        #pragma unroll
        for (int tn = 0; tn < 4; ++tn)
            acc[tn] = __builtin_amdgcn_mfma_f32_16x16x32_bf16(Ahi0, Whi[tn][0], acc[tn], 0, 0, 0);
        #pragma unroll
        for (int tn = 0; tn < 4; ++tn)
            acc[tn] = __builtin_amdgcn_mfma_f32_16x16x32_bf16(Ahi1, Whi[tn][1], acc[tn], 0, 0, 0);
        #pragma unroll
        for (int tn = 0; tn < 4; ++tn)
            acc[tn] = __builtin_amdgcn_mfma_f32_16x16x32_bf16(Ahi0, Wlo[tn][0], acc[tn], 0, 0, 0);
        #pragma unroll
        for (int tn = 0; tn < 4; ++tn)
            acc[tn] = __builtin_amdgcn_mfma_f32_16x16x32_bf16(Ahi1, Wlo[tn][1], acc[tn], 0, 0, 0);
        #pragma unroll
        for (int tn = 0; tn < 4; ++tn)
            acc[tn] = __builtin_amdgcn_mfma_f32_16x16x32_bf16(Alo0, Whi[tn][0], acc[tn], 0, 0, 0);
        #pragma unroll
        for (int tn = 0; tn < 4; ++tn)
            acc[tn] = __builtin_amdgcn_mfma_f32_16x16x32_bf16(Alo1, Whi[tn][1], acc[tn], 0, 0, 0);

        // C layout: col = ln&15 (gate within tile), row = (ln>>4)*4 + reg.
        // Lanes 0..15 hold rows 0..3 = batches 0..3 in regs 0..3 -> b128 write.
        if (ln < 16) {
            #pragma unroll
            for (int tn = 0; tn < 4; ++tn)
                *(f32x4*)&g_raw[(wv * 64 + tn * 16 + ln) * 4] = acc[tn];
        }
        __syncthreads();

        // ===== phase 2: activations + state update =====
        // reads are g_raw[tid + 256*g] -> linear, conflict-free
        const float xt = x_lds[t][pb];
        float gi = g_raw[tid +   0] + fmaf(xt, wih[0], bias[0]);
        float gf = g_raw[tid + 256] + fmaf(xt, wih[1], bias[1]);
        float gg = g_raw[tid + 512] + fmaf(xt, wih[2], bias[2]);
        float go = g_raw[tid + 768] + fmaf(xt, wih[3], bias[3]);

        const float ig = sigm(gi);
        const float fg = sigm(gf);
        const float tg = tanh_fast(gg);
        const float og = sigm(go);

        c = fmaf(fg, c, ig * tg);
        h = og * tanh_fast(c);

        // split h -> bf16 hi/lo, store into A-fragment layout
        __bf16 hh = (__bf16)h;
        float  hr = h - (float)hh;
        __bf16 hl = (__bf16)hr;
        *(__bf16*)(hA + ha_off(0, pb, pj * 2)) = hh;
        *(__bf16*)(hA + ha_off(1, pb, pj * 2)) = hl;

        __syncthreads();
    }

    // ---- output: out[b0+b] = sum_j h[b][j]*w_lin[j] + b_lin ----
    // lane layout within wave: ln = (jloc<<2) | b ; reduce over jloc bits
    float p = h * wlin;
    #pragma unroll
    for (int off = 4; off < 64; off <<= 1)
        p += __shfl_xor(p, off, 64);
    if (ln < 4) g_raw[wv * 4 + ln] = p;    // per-wave partial for b=ln
    __syncthreads();
    if (tid < 4)
        out[b0 + tid] = g_raw[0 * 4 + tid] + g_raw[1 * 4 + tid] +
                        g_raw[2 * 4 + tid] + g_raw[3 * 4 + tid] + b_lin[0];
}

extern "C" void kernel_launch(void* const* d_in, const int* in_sizes, int n_in,
                              void* d_out, int out_size, void* d_ws, size_t ws_size,
                              hipStream_t stream) {
    const float* x     = (const float*)d_in[0];
    const float* w_ih  = (const float*)d_in[1];
    const float* w_hh  = (const float*)d_in[2];
    const float* b_ih  = (const float*)d_in[3];
    const float* b_hh  = (const float*)d_in[4];
    const float* w_lin = (const float*)d_in[5];
    const float* b_lin = (const float*)d_in[6];
    float* out = (float*)d_out;

    dim3 grid(Bsz / NB);   // 512
    dim3 block(256);
    lstm_mfma<<<grid, block, 0, stream>>>(x, w_ih, w_hh, b_ih, b_hh,
                                          w_lin, b_lin, out);
}